// Round 2
// baseline (603.042 us; speedup 1.0000x reference)
//
#include <hip/hip_runtime.h>

// GRU stack (L=6, H=2048, batch=1) + LayerNorm + Linear head. ALL fp32.
// Pure matvec -> memory-bound on ~621 MB of fp32 weights (~99 us roofline).

constexpr int HID = 2048;
constexpr int NL  = 6;
constexpr int G3  = 3 * HID;   // 6144 gate rows per layer

__device__ __forceinline__ float wave_sum(float s){
  #pragma unroll
  for(int off = 32; off; off >>= 1) s += __shfl_down(s, off, 64);
  return s;  // lane 0 holds total
}

// 2048-length fp32 dot, one wave: 8 x float4 per lane, fully unrolled for MLP
__device__ __forceinline__ float dot_f32(const float* __restrict__ row,
                                         const float* __restrict__ v, int lane){
  const float4* r4 = (const float4*)row;
  const float4* v4 = (const float4*)v;
  float s = 0.f;
  #pragma unroll
  for(int it = 0; it < 8; ++it){
    int idx = lane + 64 * it;        // 64 lanes x 8 iters x 4 floats = 2048
    float4 w = r4[idx], a = v4[idx];
    s += w.x * a.x + w.y * a.y + w.z * a.z + w.w * a.w;
  }
  return s;
}

// One block per output element j. Waves 0-2: w_ih rows {j, j+H, j+2H} . inp
// Waves 3-5: w_hh rows . hidden[l]. Then GRU cell update by thread 0.
__global__ __launch_bounds__(384) void k_layer(
    const float* __restrict__ w_ih_l,
    const float* __restrict__ w_hh_l,
    const float* __restrict__ b_ih_l,
    const float* __restrict__ b_hh_l,
    const float* __restrict__ h_l,
    const float* __restrict__ inp,
    float* __restrict__ h_new_ws,   // feeds next layer
    float* __restrict__ h_new_out)  // new_hidden output slot
{
  int j    = blockIdx.x;          // 0..2047
  int wave = threadIdx.x >> 6;    // 0..5
  int lane = threadIdx.x & 63;
  __shared__ float sums[6];
  float s;
  if(wave < 3){
    s = dot_f32(w_ih_l + (size_t)(wave * HID + j) * HID, inp, lane);
  } else {
    s = dot_f32(w_hh_l + (size_t)((wave - 3) * HID + j) * HID, h_l, lane);
  }
  s = wave_sum(s);
  if(lane == 0) sums[wave] = s;
  __syncthreads();
  if(threadIdx.x == 0){
    float gi_r = sums[0] + b_ih_l[j];
    float gi_z = sums[1] + b_ih_l[HID + j];
    float gi_n = sums[2] + b_ih_l[2 * HID + j];
    float gh_r = sums[3] + b_hh_l[j];
    float gh_z = sums[4] + b_hh_l[HID + j];
    float gh_n = sums[5] + b_hh_l[2 * HID + j];
    float r = 1.f / (1.f + __expf(-(gi_r + gh_r)));
    float z = 1.f / (1.f + __expf(-(gi_z + gh_z)));
    float n = tanhf(gi_n + r * gh_n);
    float hn = (1.f - z) * n + z * h_l[j];
    h_new_ws[j]  = hn;
    h_new_out[j] = hn;
  }
}

__global__ __launch_bounds__(256) void k_layernorm(
    const float* __restrict__ h,
    const float* __restrict__ gamma,
    const float* __restrict__ beta,
    float* __restrict__ out)
{
  __shared__ float rs[4], rs2[4];
  __shared__ float s_mu, s_istd;
  int wave = threadIdx.x >> 6, lane = threadIdx.x & 63;
  float s = 0.f, s2 = 0.f;
  for(int i = threadIdx.x; i < HID; i += 256){ float v = h[i]; s += v; s2 += v * v; }
  #pragma unroll
  for(int off = 32; off; off >>= 1){ s += __shfl_down(s, off, 64); s2 += __shfl_down(s2, off, 64); }
  if(lane == 0){ rs[wave] = s; rs2[wave] = s2; }
  __syncthreads();
  if(threadIdx.x == 0){
    float S  = rs[0] + rs[1] + rs[2] + rs[3];
    float S2 = rs2[0] + rs2[1] + rs2[2] + rs2[3];
    float m   = S * (1.f / HID);
    float var = S2 * (1.f / HID) - m * m;
    s_mu = m; s_istd = rsqrtf(var + 1e-5f);
  }
  __syncthreads();
  float mu = s_mu, istd = s_istd;
  for(int i = threadIdx.x; i < HID; i += 256){
    out[i] = (h[i] - mu) * istd * gamma[i] + beta[i];
  }
}

// pred[o] = ln_out . lin_w[o] + lin_b[o] + x[o]; one wave per output row
__global__ __launch_bounds__(256) void k_linear(
    const float* __restrict__ v,
    const float* __restrict__ lin_w,
    const float* __restrict__ lin_b,
    const float* __restrict__ x,
    float* __restrict__ pred)
{
  int o    = blockIdx.x * 4 + (threadIdx.x >> 6);
  int lane = threadIdx.x & 63;
  float s = dot_f32(lin_w + (size_t)o * HID, v, lane);
  s = wave_sum(s);
  if(lane == 0) pred[o] = s + lin_b[o] + x[o];
}

extern "C" void kernel_launch(void* const* d_in, const int* in_sizes, int n_in,
                              void* d_out, int out_size, void* d_ws, size_t ws_size,
                              hipStream_t stream){
  const float* x      = (const float*)d_in[0];
  const float* hidden = (const float*)d_in[1];
  const float* w_ih   = (const float*)d_in[2];
  const float* w_hh   = (const float*)d_in[3];
  const float* b_ih   = (const float*)d_in[4];
  const float* b_hh   = (const float*)d_in[5];
  const float* gamma  = (const float*)d_in[6];
  const float* beta   = (const float*)d_in[7];
  const float* lin_w  = (const float*)d_in[8];
  const float* lin_b  = (const float*)d_in[9];
  float* out = (float*)d_out;  // [pred(2048) | new_hidden(6*2048)]

  // ws layout (fp32): activation chain buf[l*HID], l=0..6 used as:
  //   layer l input  = (l==0 ? x : buf[(l-1)*HID])
  //   layer l output = buf[l*HID];  ln_out at buf[6*HID]
  float* buf = (float*)d_ws;

  for(int l = 0; l < NL; ++l){
    k_layer<<<HID, 384, 0, stream>>>(
        w_ih + (size_t)l * G3 * HID,
        w_hh + (size_t)l * G3 * HID,
        b_ih + (size_t)l * G3,
        b_hh + (size_t)l * G3,
        hidden + (size_t)l * HID,
        (l == 0) ? x : buf + (size_t)(l - 1) * HID,
        buf + (size_t)l * HID,
        out + HID + (size_t)l * HID);
  }
  k_layernorm<<<1, 256, 0, stream>>>(buf + 5 * HID, gamma, beta, buf + 6 * HID);
  k_linear<<<HID / 4, 256, 0, stream>>>(buf + 6 * HID, lin_w, lin_b, x, out);
}